// Round 4
// baseline (2702.394 us; speedup 1.0000x reference)
//
#include <hip/hip_runtime.h>

#define NLV 16
#define TBL (1u << 19)
#define TMASK (TBL - 1u)
#define P1 2654435761u
#define P2 805459861u

typedef float vf2 __attribute__((ext_vector_type(2)));
typedef float vf4 __attribute__((ext_vector_type(4)));

// ---------------------------------------------------------------------------
// Pass 1: level-major gather for levels [k0, 16). 4 points per thread.
// Grid ordered level-major so concurrently-resident blocks share one <=4MB
// table -> table is L2-resident per XCD. Table gathers use non-temporal
// loads (skip L1 allocation: 4MB table never L1-hits anyway).
// ws layout: [L-k0][n] float2, coalesced writes.
// ---------------------------------------------------------------------------
__global__ __launch_bounds__(256) void ngp_gather_levels(
    const float* __restrict__ xyz,
    const float* __restrict__ tables,
    const int* __restrict__ resolutions,
    vf2* __restrict__ ws,
    int n, int nbPerLevel, int k0)
{
    int L = blockIdx.x / nbPerLevel + k0;
    int chunk = blockIdx.x % nbPerLevel;
    int p0 = chunk * 1024 + (int)threadIdx.x;

    float res = (float)resolutions[L];
    const vf2* __restrict__ tab = (const vf2*)tables + (size_t)L * TBL;
    vf2* __restrict__ wl = ws + (size_t)(L - k0) * n;

    unsigned idx[4][8];
    float wgt[4][8];

#pragma unroll
    for (int q = 0; q < 4; ++q) {
        int p = p0 + q * 256;
        int pp = (p < n) ? p : (n - 1);
        float x = xyz[(size_t)pp * 3 + 0];
        float y = xyz[(size_t)pp * 3 + 1];
        float z = xyz[(size_t)pp * 3 + 2];
        float ux = x * 0.5f + 0.5f;
        float uy = y * 0.5f + 0.5f;
        float uz = z * 0.5f + 0.5f;
        float px = ux * res, py = uy * res, pz = uz * res;
        float fx = floorf(px), fy = floorf(py), fz = floorf(pz);
        float wx = px - fx, wy = py - fy, wz = pz - fz;
        unsigned cx = (unsigned)fx, cy = (unsigned)fy, cz = (unsigned)fz;
        unsigned hx0 = cx, hx1 = cx + 1u;           // prime_x == 1
        unsigned hy0 = cy * P1, hy1 = hy0 + P1;     // (c+1)*P == c*P + P
        unsigned hz0 = cz * P2, hz1 = hz0 + P2;
        float vx = 1.0f - wx, vy = 1.0f - wy, vz = 1.0f - wz;
#pragma unroll
        for (int c = 0; c < 8; ++c) {
            idx[q][c] = ((((c & 1) ? hx1 : hx0) ^
                          ((c & 2) ? hy1 : hy0) ^
                          ((c & 4) ? hz1 : hz0)) & TMASK);
            wgt[q][c] = ((c & 1) ? wx : vx) *
                        ((c & 2) ? wy : vy) *
                        ((c & 4) ? wz : vz);
        }
    }

    // issue all 32 gathers before consuming any (MLP)
    vf2 f[4][8];
#pragma unroll
    for (int q = 0; q < 4; ++q)
#pragma unroll
        for (int c = 0; c < 8; ++c)
            f[q][c] = __builtin_nontemporal_load(&tab[idx[q][c]]);

#pragma unroll
    for (int q = 0; q < 4; ++q) {
        float a0 = 0.0f, a1 = 0.0f;
#pragma unroll
        for (int c = 0; c < 8; ++c) {
            a0 += f[q][c].x * wgt[q][c];
            a1 += f[q][c].y * wgt[q][c];
        }
        int p = p0 + q * 256;
        if (p < n) {
            vf2 r; r.x = a0; r.y = a1;
            wl[p] = r;
        }
    }
}

// ---------------------------------------------------------------------------
// Pass 2 (full-ws path): pure streaming transpose-merge, zero gathers.
// Thread handles 2 adjacent points: 16 vf4 stream reads (nt), writes two
// 128B output rows as vf4s.
// ---------------------------------------------------------------------------
__global__ __launch_bounds__(256) void ngp_transpose_merge(
    const vf2* __restrict__ ws,
    float* __restrict__ out, int n)
{
    int t = blockIdx.x * 256 + threadIdx.x;
    int p = t * 2;
    if (p >= n) return;

    if (p + 1 < n) {
        vf4 m[NLV];
#pragma unroll
        for (int L = 0; L < NLV; ++L)
            m[L] = __builtin_nontemporal_load(
                (const vf4*)(ws + (size_t)L * n + p));
        vf4* o0 = (vf4*)(out + (size_t)p * (NLV * 2));
#pragma unroll
        for (int i = 0; i < 8; ++i) {
            vf4 r; r.x = m[2 * i].x; r.y = m[2 * i].y;
            r.z = m[2 * i + 1].x; r.w = m[2 * i + 1].y;
            o0[i] = r;
        }
        vf4* o1 = (vf4*)(out + (size_t)(p + 1) * (NLV * 2));
#pragma unroll
        for (int i = 0; i < 8; ++i) {
            vf4 r; r.x = m[2 * i].z; r.y = m[2 * i].w;
            r.z = m[2 * i + 1].z; r.w = m[2 * i + 1].w;
            o1[i] = r;
        }
    } else {
        vf2 m[NLV];
#pragma unroll
        for (int L = 0; L < NLV; ++L)
            m[L] = ws[(size_t)L * n + p];
        vf4* o0 = (vf4*)(out + (size_t)p * (NLV * 2));
#pragma unroll
        for (int i = 0; i < 8; ++i) {
            vf4 r; r.x = m[2 * i].x; r.y = m[2 * i].y;
            r.z = m[2 * i + 1].x; r.w = m[2 * i + 1].y;
            o0[i] = r;
        }
    }
}

// ---------------------------------------------------------------------------
// Pass 2 (partial-ws fallback): per-point finalize computing dense levels
// [0, K0) directly, merging [K0,16) from ws. (Known-good from round 2.)
// ---------------------------------------------------------------------------
template <int K0>
__global__ __launch_bounds__(256) void ngp_finalize(
    const float* __restrict__ xyz,
    const float* __restrict__ tables,
    const int* __restrict__ resolutions,
    const vf2* __restrict__ ws,
    float* __restrict__ out, int n)
{
    int p = blockIdx.x * 256 + threadIdx.x;
    if (p >= n) return;

    float x = xyz[(size_t)p * 3 + 0];
    float y = xyz[(size_t)p * 3 + 1];
    float z = xyz[(size_t)p * 3 + 2];
    float ux = x * 0.5f + 0.5f;
    float uy = y * 0.5f + 0.5f;
    float uz = z * 0.5f + 0.5f;

    float acc[NLV * 2];

    vf2 m[NLV - K0];
#pragma unroll
    for (int L = K0; L < NLV; ++L)
        m[L - K0] = ws[(size_t)(L - K0) * n + p];

#pragma unroll
    for (int L = 0; L < K0; ++L) {
        float res = (float)resolutions[L];
        float px = ux * res, py = uy * res, pz = uz * res;
        float fx = floorf(px), fy = floorf(py), fz = floorf(pz);
        float wx = px - fx, wy = py - fy, wz = pz - fz;
        unsigned cx = (unsigned)fx, cy = (unsigned)fy, cz = (unsigned)fz;
        unsigned hx0 = cx, hx1 = cx + 1u;
        unsigned hy0 = cy * P1, hy1 = hy0 + P1;
        unsigned hz0 = cz * P2, hz1 = hz0 + P2;
        const vf2* __restrict__ tab = (const vf2*)tables + (size_t)L * TBL;
        float vx = 1.0f - wx, vy = 1.0f - wy, vz = 1.0f - wz;
        float a0 = 0.0f, a1 = 0.0f;
#pragma unroll
        for (int c = 0; c < 8; ++c) {
            unsigned h = ((c & 1) ? hx1 : hx0) ^
                         ((c & 2) ? hy1 : hy0) ^
                         ((c & 4) ? hz1 : hz0);
            vf2 f = tab[h & TMASK];
            float w = ((c & 1) ? wx : vx) *
                      ((c & 2) ? wy : vy) *
                      ((c & 4) ? wz : vz);
            a0 += f.x * w;
            a1 += f.y * w;
        }
        acc[L * 2 + 0] = a0;
        acc[L * 2 + 1] = a1;
    }

#pragma unroll
    for (int L = K0; L < NLV; ++L) {
        acc[L * 2 + 0] = m[L - K0].x;
        acc[L * 2 + 1] = m[L - K0].y;
    }

    vf4* o = (vf4*)(out + (size_t)p * (NLV * 2));
#pragma unroll
    for (int i = 0; i < 8; ++i) {
        vf4 r; r.x = acc[i * 4 + 0]; r.y = acc[i * 4 + 1];
        r.z = acc[i * 4 + 2]; r.w = acc[i * 4 + 3];
        o[i] = r;
    }
}

// ---------------------------------------------------------------------------
// Fallback: single-pass point-major kernel (ws too small).
// ---------------------------------------------------------------------------
__global__ __launch_bounds__(256) void ngp_encode_kernel(
    const float* __restrict__ xyz,
    const float* __restrict__ tables,
    const int* __restrict__ resolutions,
    float* __restrict__ out,
    int n)
{
    int p = blockIdx.x * blockDim.x + threadIdx.x;
    if (p >= n) return;

    float x = xyz[(size_t)p * 3 + 0];
    float y = xyz[(size_t)p * 3 + 1];
    float z = xyz[(size_t)p * 3 + 2];
    float ux = x * 0.5f + 0.5f;
    float uy = y * 0.5f + 0.5f;
    float uz = z * 0.5f + 0.5f;

    float acc[NLV * 2];

#pragma unroll
    for (int L = 0; L < NLV; ++L) {
        float res = (float)resolutions[L];
        float px = ux * res, py = uy * res, pz = uz * res;
        float fx = floorf(px), fy = floorf(py), fz = floorf(pz);
        float wx = px - fx, wy = py - fy, wz = pz - fz;
        unsigned cx = (unsigned)fx, cy = (unsigned)fy, cz = (unsigned)fz;
        unsigned hx0 = cx, hx1 = cx + 1u;
        unsigned hy0 = cy * P1, hy1 = hy0 + P1;
        unsigned hz0 = cz * P2, hz1 = hz0 + P2;
        const vf2* __restrict__ tab = (const vf2*)tables + (size_t)L * TBL;
        float vx = 1.0f - wx, vy = 1.0f - wy, vz = 1.0f - wz;
        float a0 = 0.0f, a1 = 0.0f;
#pragma unroll
        for (int c = 0; c < 8; ++c) {
            unsigned h = ((c & 1) ? hx1 : hx0) ^
                         ((c & 2) ? hy1 : hy0) ^
                         ((c & 4) ? hz1 : hz0);
            vf2 f = tab[h & TMASK];
            float w = ((c & 1) ? wx : vx) *
                      ((c & 2) ? wy : vy) *
                      ((c & 4) ? wz : vz);
            a0 += f.x * w;
            a1 += f.y * w;
        }
        acc[L * 2 + 0] = a0;
        acc[L * 2 + 1] = a1;
    }

    vf4* o = (vf4*)(out + (size_t)p * (NLV * 2));
#pragma unroll
    for (int i = 0; i < 8; ++i) {
        vf4 r; r.x = acc[i * 4 + 0]; r.y = acc[i * 4 + 1];
        r.z = acc[i * 4 + 2]; r.w = acc[i * 4 + 3];
        o[i] = r;
    }
}

extern "C" void kernel_launch(void* const* d_in, const int* in_sizes, int n_in,
                              void* d_out, int out_size, void* d_ws, size_t ws_size,
                              hipStream_t stream) {
    const float* xyz = (const float*)d_in[0];
    const float* tables = (const float*)d_in[1];
    const int* resolutions = (const int*)d_in[2];
    float* out = (float*)d_out;

    int n = in_sizes[0] / 3;
    int nbPerLevel = (n + 1023) / 1024;

    const size_t need0 = (size_t)(NLV - 0) * (size_t)n * sizeof(vf2);
    const size_t need2 = (size_t)(NLV - 2) * (size_t)n * sizeof(vf2);
    const size_t need5 = (size_t)(NLV - 5) * (size_t)n * sizeof(vf2);

    if (ws_size >= need0) {
        int grid1 = NLV * nbPerLevel;
        hipLaunchKernelGGL(ngp_gather_levels, dim3(grid1), dim3(256), 0, stream,
                           xyz, tables, resolutions, (vf2*)d_ws, n, nbPerLevel, 0);
        int grid2 = ((n + 1) / 2 + 255) / 256;
        hipLaunchKernelGGL(ngp_transpose_merge, dim3(grid2), dim3(256), 0, stream,
                           (const vf2*)d_ws, out, n);
    } else if (ws_size >= need2) {
        int grid1 = (NLV - 2) * nbPerLevel;
        hipLaunchKernelGGL(ngp_gather_levels, dim3(grid1), dim3(256), 0, stream,
                           xyz, tables, resolutions, (vf2*)d_ws, n, nbPerLevel, 2);
        int grid2 = (n + 255) / 256;
        hipLaunchKernelGGL((ngp_finalize<2>), dim3(grid2), dim3(256), 0, stream,
                           xyz, tables, resolutions, (const vf2*)d_ws, out, n);
    } else if (ws_size >= need5) {
        int grid1 = (NLV - 5) * nbPerLevel;
        hipLaunchKernelGGL(ngp_gather_levels, dim3(grid1), dim3(256), 0, stream,
                           xyz, tables, resolutions, (vf2*)d_ws, n, nbPerLevel, 5);
        int grid2 = (n + 255) / 256;
        hipLaunchKernelGGL((ngp_finalize<5>), dim3(grid2), dim3(256), 0, stream,
                           xyz, tables, resolutions, (const vf2*)d_ws, out, n);
    } else {
        int grid = (n + 255) / 256;
        hipLaunchKernelGGL(ngp_encode_kernel, dim3(grid), dim3(256), 0, stream,
                           xyz, tables, resolutions, out, n);
    }
}

// Round 5
// 850.387 us; speedup vs baseline: 3.1778x; 3.1778x over previous
//
#include <hip/hip_runtime.h>

#define NLV 16
#define TBL (1u << 19)
#define TMASK (TBL - 1u)
#define P1 2654435761u
#define P2 805459861u

typedef float vf2 __attribute__((ext_vector_type(2)));
typedef float vf4 __attribute__((ext_vector_type(4)));

// ---------------------------------------------------------------------------
// Pass 1: level-major gather for levels [k0, 16). 4 points per thread.
// Grid ordered level-major so the ~2048 concurrently-resident blocks all
// work on the same (or adjacent) level -> one <=4MB table per XCD L2.
// Plain loads only: nt loads proved to evict from L2 (round-4 post-mortem,
// FETCH 878MB -> 5.16GB).
// ws layout: [L-k0][n] float2, coalesced writes.
// ---------------------------------------------------------------------------
__global__ __launch_bounds__(256) void ngp_gather_levels(
    const float* __restrict__ xyz,
    const float* __restrict__ tables,
    const int* __restrict__ resolutions,
    vf2* __restrict__ ws,
    int n, int nbPerLevel, int k0)
{
    int L = blockIdx.x / nbPerLevel + k0;
    int chunk = blockIdx.x % nbPerLevel;
    int p0 = chunk * 1024 + (int)threadIdx.x;

    float res = (float)resolutions[L];
    const vf2* __restrict__ tab = (const vf2*)tables + (size_t)L * TBL;
    vf2* __restrict__ wl = ws + (size_t)(L - k0) * n;

    unsigned idx[4][8];
    float wgt[4][8];

#pragma unroll
    for (int q = 0; q < 4; ++q) {
        int p = p0 + q * 256;
        int pp = (p < n) ? p : (n - 1);
        float x = xyz[(size_t)pp * 3 + 0];
        float y = xyz[(size_t)pp * 3 + 1];
        float z = xyz[(size_t)pp * 3 + 2];
        float ux = x * 0.5f + 0.5f;
        float uy = y * 0.5f + 0.5f;
        float uz = z * 0.5f + 0.5f;
        float px = ux * res, py = uy * res, pz = uz * res;
        float fx = floorf(px), fy = floorf(py), fz = floorf(pz);
        float wx = px - fx, wy = py - fy, wz = pz - fz;
        unsigned cx = (unsigned)fx, cy = (unsigned)fy, cz = (unsigned)fz;
        unsigned hx0 = cx, hx1 = cx + 1u;           // prime_x == 1
        unsigned hy0 = cy * P1, hy1 = hy0 + P1;     // (c+1)*P == c*P + P
        unsigned hz0 = cz * P2, hz1 = hz0 + P2;
        float vx = 1.0f - wx, vy = 1.0f - wy, vz = 1.0f - wz;
#pragma unroll
        for (int c = 0; c < 8; ++c) {
            idx[q][c] = ((((c & 1) ? hx1 : hx0) ^
                          ((c & 2) ? hy1 : hy0) ^
                          ((c & 4) ? hz1 : hz0)) & TMASK);
            wgt[q][c] = ((c & 1) ? wx : vx) *
                        ((c & 2) ? wy : vy) *
                        ((c & 4) ? wz : vz);
        }
    }

    // issue all 32 gathers before consuming any (MLP)
    vf2 f[4][8];
#pragma unroll
    for (int q = 0; q < 4; ++q)
#pragma unroll
        for (int c = 0; c < 8; ++c)
            f[q][c] = tab[idx[q][c]];

#pragma unroll
    for (int q = 0; q < 4; ++q) {
        float a0 = 0.0f, a1 = 0.0f;
#pragma unroll
        for (int c = 0; c < 8; ++c) {
            a0 += f[q][c].x * wgt[q][c];
            a1 += f[q][c].y * wgt[q][c];
        }
        int p = p0 + q * 256;
        if (p < n) {
            vf2 r; r.x = a0; r.y = a1;
            wl[p] = r;
        }
    }
}

// ---------------------------------------------------------------------------
// Pass 2 (full-ws path): pure streaming transpose-merge, zero gathers.
// Thread handles 2 adjacent points: 16 vf4 stream reads, writes two
// 128B output rows as vf4s.
// ---------------------------------------------------------------------------
__global__ __launch_bounds__(256) void ngp_transpose_merge(
    const vf2* __restrict__ ws,
    float* __restrict__ out, int n)
{
    int t = blockIdx.x * 256 + threadIdx.x;
    int p = t * 2;
    if (p >= n) return;

    if (p + 1 < n) {
        vf4 m[NLV];
#pragma unroll
        for (int L = 0; L < NLV; ++L)
            m[L] = *(const vf4*)(ws + (size_t)L * n + p);
        vf4* o0 = (vf4*)(out + (size_t)p * (NLV * 2));
#pragma unroll
        for (int i = 0; i < 8; ++i) {
            vf4 r; r.x = m[2 * i].x; r.y = m[2 * i].y;
            r.z = m[2 * i + 1].x; r.w = m[2 * i + 1].y;
            o0[i] = r;
        }
        vf4* o1 = (vf4*)(out + (size_t)(p + 1) * (NLV * 2));
#pragma unroll
        for (int i = 0; i < 8; ++i) {
            vf4 r; r.x = m[2 * i].z; r.y = m[2 * i].w;
            r.z = m[2 * i + 1].z; r.w = m[2 * i + 1].w;
            o1[i] = r;
        }
    } else {
        vf2 m[NLV];
#pragma unroll
        for (int L = 0; L < NLV; ++L)
            m[L] = ws[(size_t)L * n + p];
        vf4* o0 = (vf4*)(out + (size_t)p * (NLV * 2));
#pragma unroll
        for (int i = 0; i < 8; ++i) {
            vf4 r; r.x = m[2 * i].x; r.y = m[2 * i].y;
            r.z = m[2 * i + 1].x; r.w = m[2 * i + 1].y;
            o0[i] = r;
        }
    }
}

// ---------------------------------------------------------------------------
// Pass 2 (partial-ws fallback): per-point finalize computing dense levels
// [0, K0) directly, merging [K0,16) from ws.
// ---------------------------------------------------------------------------
template <int K0>
__global__ __launch_bounds__(256) void ngp_finalize(
    const float* __restrict__ xyz,
    const float* __restrict__ tables,
    const int* __restrict__ resolutions,
    const vf2* __restrict__ ws,
    float* __restrict__ out, int n)
{
    int p = blockIdx.x * 256 + threadIdx.x;
    if (p >= n) return;

    float x = xyz[(size_t)p * 3 + 0];
    float y = xyz[(size_t)p * 3 + 1];
    float z = xyz[(size_t)p * 3 + 2];
    float ux = x * 0.5f + 0.5f;
    float uy = y * 0.5f + 0.5f;
    float uz = z * 0.5f + 0.5f;

    float acc[NLV * 2];

    vf2 m[NLV - K0];
#pragma unroll
    for (int L = K0; L < NLV; ++L)
        m[L - K0] = ws[(size_t)(L - K0) * n + p];

#pragma unroll
    for (int L = 0; L < K0; ++L) {
        float res = (float)resolutions[L];
        float px = ux * res, py = uy * res, pz = uz * res;
        float fx = floorf(px), fy = floorf(py), fz = floorf(pz);
        float wx = px - fx, wy = py - fy, wz = pz - fz;
        unsigned cx = (unsigned)fx, cy = (unsigned)fy, cz = (unsigned)fz;
        unsigned hx0 = cx, hx1 = cx + 1u;
        unsigned hy0 = cy * P1, hy1 = hy0 + P1;
        unsigned hz0 = cz * P2, hz1 = hz0 + P2;
        const vf2* __restrict__ tab = (const vf2*)tables + (size_t)L * TBL;
        float vx = 1.0f - wx, vy = 1.0f - wy, vz = 1.0f - wz;
        float a0 = 0.0f, a1 = 0.0f;
#pragma unroll
        for (int c = 0; c < 8; ++c) {
            unsigned h = ((c & 1) ? hx1 : hx0) ^
                         ((c & 2) ? hy1 : hy0) ^
                         ((c & 4) ? hz1 : hz0);
            vf2 f = tab[h & TMASK];
            float w = ((c & 1) ? wx : vx) *
                      ((c & 2) ? wy : vy) *
                      ((c & 4) ? wz : vz);
            a0 += f.x * w;
            a1 += f.y * w;
        }
        acc[L * 2 + 0] = a0;
        acc[L * 2 + 1] = a1;
    }

#pragma unroll
    for (int L = K0; L < NLV; ++L) {
        acc[L * 2 + 0] = m[L - K0].x;
        acc[L * 2 + 1] = m[L - K0].y;
    }

    vf4* o = (vf4*)(out + (size_t)p * (NLV * 2));
#pragma unroll
    for (int i = 0; i < 8; ++i) {
        vf4 r; r.x = acc[i * 4 + 0]; r.y = acc[i * 4 + 1];
        r.z = acc[i * 4 + 2]; r.w = acc[i * 4 + 3];
        o[i] = r;
    }
}

// ---------------------------------------------------------------------------
// Fallback: single-pass point-major kernel (ws too small).
// ---------------------------------------------------------------------------
__global__ __launch_bounds__(256) void ngp_encode_kernel(
    const float* __restrict__ xyz,
    const float* __restrict__ tables,
    const int* __restrict__ resolutions,
    float* __restrict__ out,
    int n)
{
    int p = blockIdx.x * blockDim.x + threadIdx.x;
    if (p >= n) return;

    float x = xyz[(size_t)p * 3 + 0];
    float y = xyz[(size_t)p * 3 + 1];
    float z = xyz[(size_t)p * 3 + 2];
    float ux = x * 0.5f + 0.5f;
    float uy = y * 0.5f + 0.5f;
    float uz = z * 0.5f + 0.5f;

    float acc[NLV * 2];

#pragma unroll
    for (int L = 0; L < NLV; ++L) {
        float res = (float)resolutions[L];
        float px = ux * res, py = uy * res, pz = uz * res;
        float fx = floorf(px), fy = floorf(py), fz = floorf(pz);
        float wx = px - fx, wy = py - fy, wz = pz - fz;
        unsigned cx = (unsigned)fx, cy = (unsigned)fy, cz = (unsigned)fz;
        unsigned hx0 = cx, hx1 = cx + 1u;
        unsigned hy0 = cy * P1, hy1 = hy0 + P1;
        unsigned hz0 = cz * P2, hz1 = hz0 + P2;
        const vf2* __restrict__ tab = (const vf2*)tables + (size_t)L * TBL;
        float vx = 1.0f - wx, vy = 1.0f - wy, vz = 1.0f - wz;
        float a0 = 0.0f, a1 = 0.0f;
#pragma unroll
        for (int c = 0; c < 8; ++c) {
            unsigned h = ((c & 1) ? hx1 : hx0) ^
                         ((c & 2) ? hy1 : hy0) ^
                         ((c & 4) ? hz1 : hz0);
            vf2 f = tab[h & TMASK];
            float w = ((c & 1) ? wx : vx) *
                      ((c & 2) ? wy : vy) *
                      ((c & 4) ? wz : vz);
            a0 += f.x * w;
            a1 += f.y * w;
        }
        acc[L * 2 + 0] = a0;
        acc[L * 2 + 1] = a1;
    }

    vf4* o = (vf4*)(out + (size_t)p * (NLV * 2));
#pragma unroll
    for (int i = 0; i < 8; ++i) {
        vf4 r; r.x = acc[i * 4 + 0]; r.y = acc[i * 4 + 1];
        r.z = acc[i * 4 + 2]; r.w = acc[i * 4 + 3];
        o[i] = r;
    }
}

extern "C" void kernel_launch(void* const* d_in, const int* in_sizes, int n_in,
                              void* d_out, int out_size, void* d_ws, size_t ws_size,
                              hipStream_t stream) {
    const float* xyz = (const float*)d_in[0];
    const float* tables = (const float*)d_in[1];
    const int* resolutions = (const int*)d_in[2];
    float* out = (float*)d_out;

    int n = in_sizes[0] / 3;
    int nbPerLevel = (n + 1023) / 1024;

    const size_t need0 = (size_t)(NLV - 0) * (size_t)n * sizeof(vf2);
    const size_t need2 = (size_t)(NLV - 2) * (size_t)n * sizeof(vf2);
    const size_t need5 = (size_t)(NLV - 5) * (size_t)n * sizeof(vf2);

    if (ws_size >= need0) {
        int grid1 = NLV * nbPerLevel;
        hipLaunchKernelGGL(ngp_gather_levels, dim3(grid1), dim3(256), 0, stream,
                           xyz, tables, resolutions, (vf2*)d_ws, n, nbPerLevel, 0);
        int grid2 = ((n + 1) / 2 + 255) / 256;
        hipLaunchKernelGGL(ngp_transpose_merge, dim3(grid2), dim3(256), 0, stream,
                           (const vf2*)d_ws, out, n);
    } else if (ws_size >= need2) {
        int grid1 = (NLV - 2) * nbPerLevel;
        hipLaunchKernelGGL(ngp_gather_levels, dim3(grid1), dim3(256), 0, stream,
                           xyz, tables, resolutions, (vf2*)d_ws, n, nbPerLevel, 2);
        int grid2 = (n + 255) / 256;
        hipLaunchKernelGGL((ngp_finalize<2>), dim3(grid2), dim3(256), 0, stream,
                           xyz, tables, resolutions, (const vf2*)d_ws, out, n);
    } else if (ws_size >= need5) {
        int grid1 = (NLV - 5) * nbPerLevel;
        hipLaunchKernelGGL(ngp_gather_levels, dim3(grid1), dim3(256), 0, stream,
                           xyz, tables, resolutions, (vf2*)d_ws, n, nbPerLevel, 5);
        int grid2 = (n + 255) / 256;
        hipLaunchKernelGGL((ngp_finalize<5>), dim3(grid2), dim3(256), 0, stream,
                           xyz, tables, resolutions, (const vf2*)d_ws, out, n);
    } else {
        int grid = (n + 255) / 256;
        hipLaunchKernelGGL(ngp_encode_kernel, dim3(grid), dim3(256), 0, stream,
                           xyz, tables, resolutions, out, n);
    }
}